// Round 2
// baseline (146.816 us; speedup 1.0000x reference)
//
#include <hip/hip_runtime.h>

// FactorizationMachine second-order term.
// out[b] = sum_k (sum_i w[idx_i,k]*x_i)^2 - sum_i sum_k (w[idx_i,k]*x_i)^2
// batch_ids sorted -> per-block binary search for segment bounds.
// One wave (64 lanes) per batch: 16 lanes per nnz element (lane&15 = k),
// 4 elements per iteration -> each 16-lane group reads one contiguous
// 64B weight row.

#define FM_K 16

__global__ __launch_bounds__(64) void FactorizationMachine_75144747810873_kernel(
    const int* __restrict__ indices,
    const int* __restrict__ batch_ids,
    const float* __restrict__ values,
    const float* __restrict__ weight,
    float* __restrict__ out,
    int nnz)
{
    const int b    = blockIdx.x;     // batch / segment id
    const int lane = threadIdx.x;    // 0..63
    const int k    = lane & 15;      // feature dim
    const int sub  = lane >> 4;      // element subgroup 0..3

    // lower_bound over sorted batch_ids (uniform across the wave; cheap)
    int lo = 0, hi = nnz;
    while (lo < hi) {
        int mid = (lo + hi) >> 1;
        if (batch_ids[mid] < b) lo = mid + 1; else hi = mid;
    }
    const int start = lo;
    hi = nnz;
    while (lo < hi) {
        int mid = (lo + hi) >> 1;
        if (batch_ids[mid] < b + 1) lo = mid + 1; else hi = mid;
    }
    const int end = lo;

    float acc  = 0.f;   // per-k partial of sum_i w_ik * x_i
    float self = 0.f;   // partial of sum_i sum_k (w_ik * x_i)^2

    for (int e = start + sub; e < end; e += 4) {
        const int   idx = indices[e];            // broadcast within 16-lane group
        const float x   = values[e];             // broadcast within 16-lane group
        const float w   = weight[(long long)idx * FM_K + k];  // 64B/group, coalesced
        const float wx  = w * x;
        acc  += wx;
        self += wx * wx;
    }

    // fold the 4 element-subgroups (same k, lanes differing in bits 4..5)
    acc += __shfl_xor(acc, 16);
    acc += __shfl_xor(acc, 32);

    // sum over k of acc^2 (within each 16-lane group; groups hold identical data)
    float sq = acc * acc;
    sq += __shfl_xor(sq, 1);
    sq += __shfl_xor(sq, 2);
    sq += __shfl_xor(sq, 4);
    sq += __shfl_xor(sq, 8);

    // self-cross: full 64-lane reduce
    self += __shfl_xor(self, 1);
    self += __shfl_xor(self, 2);
    self += __shfl_xor(self, 4);
    self += __shfl_xor(self, 8);
    self += __shfl_xor(self, 16);
    self += __shfl_xor(self, 32);

    if (lane == 0) out[b] = sq - self;
}

extern "C" void kernel_launch(void* const* d_in, const int* in_sizes, int n_in,
                              void* d_out, int out_size, void* d_ws, size_t ws_size,
                              hipStream_t stream) {
    const int*   indices   = (const int*)d_in[0];
    const int*   batch_ids = (const int*)d_in[1];
    const float* values    = (const float*)d_in[2];
    const float* weight    = (const float*)d_in[3];
    float*       out       = (float*)d_out;
    const int nnz = in_sizes[0];

    // one 64-lane block per batch; out_size == BATCH (4096)
    FactorizationMachine_75144747810873_kernel<<<out_size, 64, 0, stream>>>(
        indices, batch_ids, values, weight, out, nnz);
}

// Round 3
// 120.705 us; speedup vs baseline: 1.2163x; 1.2163x over previous
//
#include <hip/hip_runtime.h>

// FactorizationMachine second-order term, v2 (latency-bound fix).
// out[b] = sum_k (sum_i w[idx_i,k]*x_i)^2 - sum_i sum_k (w[idx_i,k]*x_i)^2
//
// v1 post-mortem: 67us, HBM 10.8%, occupancy 37%, VALU 5% -> pure gather
// latency bound. Fixes:
//  - 4 lanes/row x float4: 16 weight rows in flight per wave-iteration (was 4)
//  - 2 waves per batch, 256-thread blocks: 8192 waves = 32/CU (was 16/CU)
//  - software-pipelined indices/values prefetch to break the idx->weight chain
// Cross-wave per-k sums merged through LDS BEFORE squaring.

#define FM_K 16

__global__ __launch_bounds__(256) void FactorizationMachine_75144747810873_kernel(
    const int* __restrict__ indices,
    const int* __restrict__ batch_ids,
    const float* __restrict__ values,
    const float* __restrict__ weight,
    float* __restrict__ out,
    int nnz, int nbatch)
{
    const int tid  = threadIdx.x;
    const int wave = tid >> 6;        // 0..3
    const int lane = tid & 63;
    const int kq   = lane & 3;        // k-quad: covers k = 4*kq .. 4*kq+3
    const int sub  = lane >> 2;       // row subgroup 0..15
    const int wip  = wave & 1;        // wave-in-pair
    const int pair = wave >> 1;       // 0..1 -> batch within block

    const int b = blockIdx.x * 2 + pair;
    const bool bvalid = (b < nbatch);

    __shared__ float4 accbuf[4][4];   // [wave][kq]
    __shared__ float  selfbuf[4];

    float4 acc  = make_float4(0.f, 0.f, 0.f, 0.f);
    float  self = 0.f;

    if (bvalid) {
        // lower_bound / upper_bound over sorted batch_ids (wave-uniform)
        int lo = 0, hi = nnz;
        while (lo < hi) {
            int mid = (lo + hi) >> 1;
            if (batch_ids[mid] < b) lo = mid + 1; else hi = mid;
        }
        const int start = lo;
        hi = nnz;
        while (lo < hi) {
            int mid = (lo + hi) >> 1;
            if (batch_ids[mid] < b + 1) lo = mid + 1; else hi = mid;
        }
        const int end = lo;

        // each wave-pair splits the segment: this wave does rows
        // e = start + sub + wip*16, stride 32
        int e = start + sub + wip * 16;
        bool valid = (e < end);
        int   idx = 0;
        float x   = 0.f;
        if (valid) { idx = indices[e]; x = values[e]; }

        while (valid) {
            // prefetch next iteration's idx/value while weight load is in flight
            const int  e2 = e + 32;
            const bool v2 = (e2 < end);
            int   idx2 = 0;
            float x2   = 0.f;
            if (v2) { idx2 = indices[e2]; x2 = values[e2]; }

            const float4 w4 = *reinterpret_cast<const float4*>(
                weight + (long long)idx * FM_K + kq * 4);
            const float4 wx = make_float4(w4.x * x, w4.y * x, w4.z * x, w4.w * x);
            acc.x += wx.x; acc.y += wx.y; acc.z += wx.z; acc.w += wx.w;
            self  += wx.x * wx.x + wx.y * wx.y + wx.z * wx.z + wx.w * wx.w;

            e = e2; valid = v2; idx = idx2; x = x2;
        }
    }

    // reduce over the 16 row-subgroups (lane bits 2..5) -> per-kq sums
    for (int off = 4; off < 64; off <<= 1) {
        acc.x += __shfl_xor(acc.x, off);
        acc.y += __shfl_xor(acc.y, off);
        acc.z += __shfl_xor(acc.z, off);
        acc.w += __shfl_xor(acc.w, off);
    }
    // full-wave reduce of self
    for (int off = 1; off < 64; off <<= 1)
        self += __shfl_xor(self, off);

    if (lane < 4)  accbuf[wave][lane] = acc;   // lane == kq here
    if (lane == 0) selfbuf[wave] = self;
    __syncthreads();

    // combine the two waves of each pair, square, reduce over k, write
    if (wip == 0 && bvalid) {
        const float4 a0 = accbuf[wave][kq];
        const float4 a1 = accbuf[wave + 1][kq];
        const float4 s  = make_float4(a0.x + a1.x, a0.y + a1.y,
                                      a0.z + a1.z, a0.w + a1.w);
        float sq = s.x * s.x + s.y * s.y + s.z * s.z + s.w * s.w;
        sq += __shfl_xor(sq, 1);
        sq += __shfl_xor(sq, 2);   // sum over the 4 kq lanes (replicated groups)
        const float selftot = selfbuf[wave] + selfbuf[wave + 1];
        if (lane == 0) out[b] = sq - selftot;
    }
}

extern "C" void kernel_launch(void* const* d_in, const int* in_sizes, int n_in,
                              void* d_out, int out_size, void* d_ws, size_t ws_size,
                              hipStream_t stream) {
    const int*   indices   = (const int*)d_in[0];
    const int*   batch_ids = (const int*)d_in[1];
    const float* values    = (const float*)d_in[2];
    const float* weight    = (const float*)d_in[3];
    float*       out       = (float*)d_out;
    const int nnz = in_sizes[0];

    const int grid = (out_size + 1) / 2;   // 2 batches per 256-thread block
    FactorizationMachine_75144747810873_kernel<<<grid, 256, 0, stream>>>(
        indices, batch_ids, values, weight, out, nnz, out_size);
}

// Round 4
// 111.312 us; speedup vs baseline: 1.3190x; 1.0844x over previous
//
#include <hip/hip_runtime.h>

// FactorizationMachine second-order term, v3.
// out[b] = sum_k (sum_i w[idx_i,k]*x_i)^2 - sum_i sum_k (w[idx_i,k]*x_i)^2
//
// v2 post-mortem: kernel ~38us (fell out of rocprof top-5 under the 40us
// harness ws-fills). Remaining costs: per-block binary-search prologue
// (~40 dependent loads), shallow gather pipeline (1KiB/wave in flight),
// exactly-1x residency (no tail balancing). v3:
//  - splits precompute kernel: boundary scatter over sorted batch_ids;
//    main kernel reads segment bounds with 2 loads (no binary search)
//  - 4x unrolled gather: 64 rows (4KiB) in flight per wave-iteration;
//    avg segment (200 rows) -> most waves do ONE iteration
//  - 1 batch per 256-thread block, 4 waves round-robin 16-row granules:
//    16384 waves = 2x residency for load balance

#define FM_K 16

// ---- Kernel A: segment-boundary scatter -> splits[0..nbatch] in d_ws ----
// splits[b] = lower_bound(batch_ids, b); each entry written exactly once.
__global__ __launch_bounds__(256) void fm_splits_kernel(
    const int* __restrict__ batch_ids,
    int* __restrict__ splits,
    int nnz, int nbatch)
{
    const int e = blockIdx.x * 256 + threadIdx.x;
    if (e > nnz) return;
    if (e == 0) {
        const int cur = batch_ids[0];
        for (int b = 0; b <= cur; ++b) splits[b] = 0;
    } else if (e == nnz) {
        const int prev = batch_ids[nnz - 1];
        for (int b = prev + 1; b <= nbatch; ++b) splits[b] = nnz;
    } else {
        const int prev = batch_ids[e - 1];
        const int cur  = batch_ids[e];
        for (int b = prev + 1; b <= cur; ++b) splits[b] = e;
    }
}

// ---- Kernel B: per-batch FM reduction ----
__global__ __launch_bounds__(256) void FactorizationMachine_75144747810873_kernel(
    const int* __restrict__ indices,
    const float* __restrict__ values,
    const float* __restrict__ weight,
    const int* __restrict__ splits,
    float* __restrict__ out)
{
    const int tid  = threadIdx.x;
    const int wave = tid >> 6;        // 0..3
    const int lane = tid & 63;
    const int kq   = lane & 3;        // k-quad: k = 4*kq .. 4*kq+3
    const int sub  = lane >> 2;       // row-in-granule 0..15

    const int b     = blockIdx.x;
    const int start = splits[b];
    const int end   = splits[b + 1];

    float4 acc  = make_float4(0.f, 0.f, 0.f, 0.f);
    float  self = 0.f;

    // granule g (16 rows) handled by wave g%4; 4 granules per wave-iteration.
    // e(t,u) = start + 256*t + 16*(wave + 4*u) + sub
    for (int base = start + 16 * wave; base < end; base += 256) {
        int   idxv[4];
        float xv[4];
#pragma unroll
        for (int u = 0; u < 4; ++u) {
            const int  e = base + 64 * u + sub;
            const bool v = (e < end);
            idxv[u] = v ? indices[e] : 0;   // row 0 gather nullified by x=0
            xv[u]   = v ? values[e]  : 0.f;
        }
#pragma unroll
        for (int u = 0; u < 4; ++u) {
            const float4 w4 = *reinterpret_cast<const float4*>(
                weight + idxv[u] * FM_K + kq * 4);   // fits 32-bit: <16M floats
            const float x = xv[u];
            const float4 wx = make_float4(w4.x * x, w4.y * x, w4.z * x, w4.w * x);
            acc.x += wx.x; acc.y += wx.y; acc.z += wx.z; acc.w += wx.w;
            self  += wx.x * wx.x + wx.y * wx.y + wx.z * wx.z + wx.w * wx.w;
        }
    }

    // reduce over the 16 row-subgroups (lane bits 2..5) -> per-kq partial sums
#pragma unroll
    for (int off = 4; off < 64; off <<= 1) {
        acc.x += __shfl_xor(acc.x, off);
        acc.y += __shfl_xor(acc.y, off);
        acc.z += __shfl_xor(acc.z, off);
        acc.w += __shfl_xor(acc.w, off);
    }
    // full-wave reduce of self
#pragma unroll
    for (int off = 1; off < 64; off <<= 1)
        self += __shfl_xor(self, off);

    __shared__ float4 accbuf[4][4];   // [wave][kq]
    __shared__ float  selfbuf[4];
    if (sub == 0)  accbuf[wave][kq] = acc;   // lanes 0..3 of each wave
    if (lane == 0) selfbuf[wave] = self;
    __syncthreads();

    if (wave == 0) {
        // all 64 lanes participate (uniform per kq group) -> shuffles are safe
        const float4 a0 = accbuf[0][kq];
        const float4 a1 = accbuf[1][kq];
        const float4 a2 = accbuf[2][kq];
        const float4 a3 = accbuf[3][kq];
        const float4 s  = make_float4(a0.x + a1.x + a2.x + a3.x,
                                      a0.y + a1.y + a2.y + a3.y,
                                      a0.z + a1.z + a2.z + a3.z,
                                      a0.w + a1.w + a2.w + a3.w);
        float sq = s.x * s.x + s.y * s.y + s.z * s.z + s.w * s.w;
        sq += __shfl_xor(sq, 1);
        sq += __shfl_xor(sq, 2);   // sum over the 4 kq groups
        const float selftot = selfbuf[0] + selfbuf[1] + selfbuf[2] + selfbuf[3];
        if (lane == 0) out[b] = sq - selftot;
    }
}

extern "C" void kernel_launch(void* const* d_in, const int* in_sizes, int n_in,
                              void* d_out, int out_size, void* d_ws, size_t ws_size,
                              hipStream_t stream) {
    const int*   indices   = (const int*)d_in[0];
    const int*   batch_ids = (const int*)d_in[1];
    const float* values    = (const float*)d_in[2];
    const float* weight    = (const float*)d_in[3];
    float*       out       = (float*)d_out;
    int*         splits    = (int*)d_ws;            // (out_size+1) ints
    const int nnz = in_sizes[0];

    fm_splits_kernel<<<(nnz + 1 + 255) / 256, 256, 0, stream>>>(
        batch_ids, splits, nnz, out_size);
    FactorizationMachine_75144747810873_kernel<<<out_size, 256, 0, stream>>>(
        indices, values, weight, splits, out);
}

// Round 5
// 110.590 us; speedup vs baseline: 1.3276x; 1.0065x over previous
//
#include <hip/hip_runtime.h>

// FactorizationMachine second-order term, v4.
// out[b] = sum_k (sum_i w[idx_i,k]*x_i)^2 - sum_i sum_k (w[idx_i,k]*x_i)^2
//
// v3 post-mortem: kernels ~29us total (under the 41us harness ws-fill in
// top-5; inferred from dur deltas: 111.3 - ~82 harness floor). In-flight
// bytes (128KiB/CU) far exceed the BW-latency product -> we sit at the
// random-64B-gather DRAM efficiency wall (~2.3TB/s effective on 57MB).
// v4 shaves the margins:
//  - nontemporal loads on streamed indices/values/batch_ids (preserve L2
//    for duplicate weight-row hits, ~31% of gathers)
//  - all 4 gather loads issued into regs before any FMA (4KiB/wave
//    outstanding guaranteed)
//  - int2 splits load (one transaction for both segment bounds)

#define FM_K 16

// ---- Kernel A: segment-boundary scatter -> splits[0..nbatch] in d_ws ----
__global__ __launch_bounds__(256) void fm_splits_kernel(
    const int* __restrict__ batch_ids,
    int* __restrict__ splits,
    int nnz, int nbatch)
{
    const int e = blockIdx.x * 256 + threadIdx.x;
    if (e > nnz) return;
    if (e == 0) {
        const int cur = __builtin_nontemporal_load(batch_ids);
        for (int b = 0; b <= cur; ++b) splits[b] = 0;
    } else if (e == nnz) {
        const int prev = __builtin_nontemporal_load(batch_ids + nnz - 1);
        for (int b = prev + 1; b <= nbatch; ++b) splits[b] = nnz;
    } else {
        const int prev = __builtin_nontemporal_load(batch_ids + e - 1);
        const int cur  = __builtin_nontemporal_load(batch_ids + e);
        for (int b = prev + 1; b <= cur; ++b) splits[b] = e;
    }
}

// ---- Kernel B: per-batch FM reduction ----
__global__ __launch_bounds__(256) void FactorizationMachine_75144747810873_kernel(
    const int* __restrict__ indices,
    const float* __restrict__ values,
    const float* __restrict__ weight,
    const int* __restrict__ splits,
    float* __restrict__ out)
{
    const int tid  = threadIdx.x;
    const int wave = tid >> 6;        // 0..3
    const int lane = tid & 63;
    const int kq   = lane & 3;        // k-quad: k = 4*kq .. 4*kq+3
    const int sub  = lane >> 2;       // row-in-granule 0..15

    const int b = blockIdx.x;
    const int2 se    = *reinterpret_cast<const int2*>(splits + b);
    const int  start = se.x;
    const int  end   = se.y;

    float4 acc  = make_float4(0.f, 0.f, 0.f, 0.f);
    float  self = 0.f;

    // granule g (16 rows) handled by wave g%4; 4 granules per wave-iteration.
    for (int base = start + 16 * wave; base < end; base += 256) {
        int   idxv[4];
        float xv[4];
#pragma unroll
        for (int u = 0; u < 4; ++u) {
            const int  e = base + 64 * u + sub;
            const bool v = (e < end);
            idxv[u] = v ? __builtin_nontemporal_load(indices + e) : 0;
            xv[u]   = v ? __builtin_nontemporal_load(values + e)  : 0.f;
        }
        // issue all 4 gathers before any FMA: 64B/lane outstanding
        float4 w4v[4];
#pragma unroll
        for (int u = 0; u < 4; ++u)
            w4v[u] = *reinterpret_cast<const float4*>(
                weight + idxv[u] * FM_K + kq * 4);   // <16M floats: 32-bit ok
#pragma unroll
        for (int u = 0; u < 4; ++u) {
            const float x = xv[u];
            const float4 wx = make_float4(w4v[u].x * x, w4v[u].y * x,
                                          w4v[u].z * x, w4v[u].w * x);
            acc.x += wx.x; acc.y += wx.y; acc.z += wx.z; acc.w += wx.w;
            self  += wx.x * wx.x + wx.y * wx.y + wx.z * wx.z + wx.w * wx.w;
        }
    }

    // reduce over the 16 row-subgroups (lane bits 2..5) -> per-kq partials
#pragma unroll
    for (int off = 4; off < 64; off <<= 1) {
        acc.x += __shfl_xor(acc.x, off);
        acc.y += __shfl_xor(acc.y, off);
        acc.z += __shfl_xor(acc.z, off);
        acc.w += __shfl_xor(acc.w, off);
    }
    // full-wave reduce of self
#pragma unroll
    for (int off = 1; off < 64; off <<= 1)
        self += __shfl_xor(self, off);

    __shared__ float4 accbuf[4][4];   // [wave][kq]
    __shared__ float  selfbuf[4];
    if (sub == 0)  accbuf[wave][kq] = acc;
    if (lane == 0) selfbuf[wave] = self;
    __syncthreads();

    if (wave == 0) {
        const float4 a0 = accbuf[0][kq];
        const float4 a1 = accbuf[1][kq];
        const float4 a2 = accbuf[2][kq];
        const float4 a3 = accbuf[3][kq];
        const float4 s  = make_float4(a0.x + a1.x + a2.x + a3.x,
                                      a0.y + a1.y + a2.y + a3.y,
                                      a0.z + a1.z + a2.z + a3.z,
                                      a0.w + a1.w + a2.w + a3.w);
        float sq = s.x * s.x + s.y * s.y + s.z * s.z + s.w * s.w;
        sq += __shfl_xor(sq, 1);
        sq += __shfl_xor(sq, 2);   // sum over the 4 kq groups
        const float selftot = selfbuf[0] + selfbuf[1] + selfbuf[2] + selfbuf[3];
        if (lane == 0) out[b] = sq - selftot;
    }
}

extern "C" void kernel_launch(void* const* d_in, const int* in_sizes, int n_in,
                              void* d_out, int out_size, void* d_ws, size_t ws_size,
                              hipStream_t stream) {
    const int*   indices   = (const int*)d_in[0];
    const int*   batch_ids = (const int*)d_in[1];
    const float* values    = (const float*)d_in[2];
    const float* weight    = (const float*)d_in[3];
    float*       out       = (float*)d_out;
    int*         splits    = (int*)d_ws;            // (out_size+1) ints
    const int nnz = in_sizes[0];

    fm_splits_kernel<<<(nnz + 1 + 255) / 256, 256, 0, stream>>>(
        batch_ids, splits, nnz, out_size);
    FactorizationMachine_75144747810873_kernel<<<out_size, 256, 0, stream>>>(
        indices, values, weight, splits, out);
}